// Round 11
// baseline (73.792 us; speedup 1.0000x reference)
//
#include <hip/hip_runtime.h>
#include <float.h>
#include <math.h>

typedef __attribute__((ext_vector_type(8))) short short8;
typedef __attribute__((ext_vector_type(8))) _Float16 half8;
typedef __attribute__((ext_vector_type(4))) float f32x4;

constexpr int B_N  = 8192;
constexpr int D_K  = 128;
constexpr int K_AUG = 192;            // 128 real dims + 64 one-hot penalty dims
constexpr int NKQ  = K_AUG / 8;       // 24 k-groups of 8
constexpr int NCLS = 50;
constexpr int NCHUNK = 16;            // 512 cols per chunk
constexpr int CCOLS = 512;
constexpr int NPBLK = 32;
constexpr float C_SCALE = 28.853900817779268f;  // 20*log2(e), folded into A real dims
constexpr float PEN  = 4096.0f;                 // same-class penalty (base-2 units)
constexpr float THR  = 40.0f;                   // defer-rescale threshold
constexpr float NEG_LOW = -1.0e5f;

__device__ __forceinline__ float exp2fast(float x) { return __builtin_amdgcn_exp2f(x); }

// ---------------- prep: augmented A (scaled, -PEN one-hot) and k-major augmented B ----------------
// aH: [row][192] f16 row-major.  bT: [kq 0..23][col 0..8191][e 0..7] f16.
__global__ void prep_kernel(const float* __restrict__ a, const float* __restrict__ b,
                            const int* __restrict__ labels,
                            short* __restrict__ aH, short* __restrict__ bT)
{
    const int NA = B_N * NKQ;                       // 196608 A-threads: one per (row,kq)
    int i = blockIdx.x * blockDim.x + threadIdx.x;
    if (i < NA) {
        int row = i / NKQ, kq = i - row * NKQ;
        short8 h;
        if (kq < 16) {
            const f32x4* sp = (const f32x4*)(a + (size_t)row * D_K + kq * 8);
            f32x4 v0 = sp[0], v1 = sp[1];
#pragma unroll
            for (int e = 0; e < 4; ++e) {
                h[e]     = __builtin_bit_cast(short, (_Float16)(C_SCALE * v0[e]));
                h[e + 4] = __builtin_bit_cast(short, (_Float16)(C_SCALE * v1[e]));
            }
        } else {
            int lab = labels[row];
            int base = (kq - 16) * 8;
#pragma unroll
            for (int e = 0; e < 8; ++e)
                h[e] = __builtin_bit_cast(short, (lab == base + e) ? (_Float16)(-PEN)
                                                                   : (_Float16)0.0f);
        }
        *(short8*)(aH + (size_t)row * K_AUG + kq * 8) = h;
    } else if (i < NA + B_N) {
        int col = i - NA;                           // one thread per B column
        int lab = labels[col];
#pragma unroll 4
        for (int kq = 0; kq < 16; ++kq) {
            const f32x4* sp = (const f32x4*)(b + (size_t)col * D_K + kq * 8);
            f32x4 v0 = sp[0], v1 = sp[1];
            short8 h;
#pragma unroll
            for (int e = 0; e < 4; ++e) {
                h[e]     = __builtin_bit_cast(short, (_Float16)v0[e]);
                h[e + 4] = __builtin_bit_cast(short, (_Float16)v1[e]);
            }
            *(short8*)(bT + ((size_t)kq * B_N + col) * 8) = h;
        }
#pragma unroll
        for (int kq = 16; kq < 24; ++kq) {
            int base = (kq - 16) * 8;
            short8 h;
#pragma unroll
            for (int e = 0; e < 8; ++e)
                h[e] = __builtin_bit_cast(short, (lab == base + e) ? (_Float16)1.0f
                                                                   : (_Float16)0.0f);
            *(short8*)(bT + ((size_t)kq * B_N + col) * 8) = h;
        }
    }
}

// ---------------- main: penalty-GEMM + 2.5-op/cell epilogue; no labels, no LDS, no barriers ----------------
// 256 thr = 4 waves; wave = 32 rows x 512 chunk cols; K=192 (masking inside MFMA).
// acc C-in = per-row bias (-ref) -> epilogue: max3 + exp2 + add per 2 cells.
__global__ __launch_bounds__(256)
void rowstats_kernel(const short* __restrict__ aH, const short* __restrict__ bT,
                     float* __restrict__ pmx, float* __restrict__ ps)
{
    const int bid   = blockIdx.x;
    const int chunk = bid & (NCHUNK - 1);
    const int R0    = (bid >> 4) * 128;
    const int C0    = chunk * CCOLS;

    const int tid = threadIdx.x;
    const int wid = tid >> 6, l = tid & 63;
    const int l15 = l & 15, l16 = l >> 4;
    const int wrow = R0 + wid * 32;

    // A fragments (augmented): 12 x half8 = 48 VGPR
    half8 aF[2][6];
#pragma unroll
    for (int mf = 0; mf < 2; ++mf) {
        const int arow = wrow + mf * 16 + l15;
#pragma unroll
        for (int ks = 0; ks < 6; ++ks)
            aF[mf][ks] = __builtin_bit_cast(half8,
                *(const short8*)(aH + (size_t)arow * K_AUG + ks * 32 + l16 * 8));
    }

    float mxr[8], sm[8];                 // running (max, sum) RELATIVE to per-row ref
    f32x4 bias[2];                       // bias[mf][r] = -ref for row i = mf*4+r
#pragma unroll
    for (int i = 0; i < 8; ++i) { mxr[i] = NEG_LOW; sm[i] = 0.0f; }
    bias[0] = f32x4{0.f, 0.f, 0.f, 0.f};
    bias[1] = f32x4{0.f, 0.f, 0.f, 0.f};

    // B fragment byte offsets (SGPR base + 32-bit voffset + imm)
    const char* cb = (const char*)bT + (size_t)C0 * 16;
    int vo[2][6];
#pragma unroll
    for (int nf = 0; nf < 2; ++nf)
#pragma unroll
        for (int ks = 0; ks < 6; ++ks)
            vo[nf][ks] = ((ks * 4 + l16) * B_N + nf * 16 + l15) * 16;

    half8 bF[2][6];
#pragma unroll
    for (int nf = 0; nf < 2; ++nf)
#pragma unroll
        for (int ks = 0; ks < 6; ++ks)
            bF[nf][ks] = __builtin_bit_cast(half8, *(const short8*)(cb + vo[nf][ks]));

    for (int tt = 0; tt < 4; ++tt) {                // 4 outer x 4 inner = 16 tiles
        const char* cbt = cb + tt * 2048;           // 4 tiles * 512B
#pragma unroll
        for (int ti = 0; ti < 4; ++ti) {
            f32x4 acc[2][2];
#pragma unroll
            for (int mf = 0; mf < 2; ++mf)
#pragma unroll
                for (int nf = 0; nf < 2; ++nf)
                    acc[mf][nf] = __builtin_amdgcn_mfma_f32_16x16x32_f16(
                        aF[mf][0], bF[nf][0], bias[mf], 0, 0, 0);
#pragma unroll
            for (int ks = 1; ks < 6; ++ks)
#pragma unroll
                for (int mf = 0; mf < 2; ++mf)
#pragma unroll
                    for (int nf = 0; nf < 2; ++nf)
                        acc[mf][nf] = __builtin_amdgcn_mfma_f32_16x16x32_f16(
                            aF[mf][ks], bF[nf][ks], acc[mf][nf], 0, 0, 0);

            // prefetch next tile (imm offset (ti+1)*512 <= 2048)
            if (!(tt == 3 && ti == 3)) {
#pragma unroll
                for (int nf = 0; nf < 2; ++nf)
#pragma unroll
                    for (int ks = 0; ks < 6; ++ks)
                        bF[nf][ks] = __builtin_bit_cast(half8,
                            *(const short8*)(cbt + vo[nf][ks] + (ti + 1) * 512));
            }

            // ---- epilogue: mask-free (penalty), bias-folded ----
            float v0[8], v1[8], nmx[8];
#pragma unroll
            for (int mf = 0; mf < 2; ++mf)
#pragma unroll
                for (int r = 0; r < 4; ++r) {
                    const int i = mf * 4 + r;
                    v0[i] = acc[mf][0][r];
                    v1[i] = acc[mf][1][r];
                    nmx[i] = fmaxf(fmaxf(mxr[i], v0[i]), v1[i]);   // -> v_max3
                }
            float tmax = fmaxf(fmaxf(fmaxf(nmx[0], nmx[1]), fmaxf(nmx[2], nmx[3])),
                               fmaxf(fmaxf(nmx[4], nmx[5]), fmaxf(nmx[6], nmx[7])));
            if (__any(tmax > THR)) {               // re-anchor (few tiles per sweep)
#pragma unroll
                for (int mf = 0; mf < 2; ++mf)
#pragma unroll
                    for (int r = 0; r < 4; ++r) {
                        const int i = mf * 4 + r;
                        float dlt = fmaxf(nmx[i], 0.0f);
                        sm[i] *= exp2fast(-dlt);
                        bias[mf][r] -= dlt;
                        nmx[i] -= dlt; v0[i] -= dlt; v1[i] -= dlt;
                    }
            }
#pragma unroll
            for (int i = 0; i < 8; ++i) {
                sm[i] += exp2fast(v0[i]) + exp2fast(v1[i]);
                mxr[i] = nmx[i];
            }
        }
    }

    // ---- tail: absolute frame, 16-lane combine ----
#pragma unroll
    for (int i = 0; i < 8; ++i) {
        float ref = -bias[i >> 2][i & 3];
        float mxa = ref + mxr[i];                  // absolute masked max (base-2 units)
        float m = mxa;
#pragma unroll
        for (int off = 1; off < 16; off <<= 1) m = fmaxf(m, __shfl_xor(m, off));
        float so = sm[i] * exp2fast(fminf(ref - m, 100.0f));   // = sum 2^(v - m)
#pragma unroll
        for (int off = 1; off < 16; off <<= 1) so += __shfl_xor(so, off);
        if (l15 == 0) {
            int row = wrow + (i >> 2) * 16 + l16 * 4 + (i & 3);
            pmx[chunk * B_N + row] = m;
            ps [chunk * B_N + row] = so;
        }
    }
}

// ---------------- per-row chunk combine + per-block class partials ----------------
__global__ void classsum_kernel(const float* __restrict__ pmx, const float* __restrict__ ps,
                                const int* __restrict__ labels,
                                float* __restrict__ partSum, unsigned int* __restrict__ partCnt)
{
    __shared__ float        csL[NCLS];
    __shared__ unsigned int ccL[NCLS];
    int t = threadIdx.x;
    if (t < NCLS) { csL[t] = 0.0f; ccL[t] = 0u; }
    __syncthreads();

    int j = blockIdx.x * blockDim.x + t;
    float m = -FLT_MAX, s = 0.0f;
#pragma unroll 4
    for (int c = 0; c < NCHUNK; ++c) {
        float m2 = pmx[(size_t)c * B_N + j];
        float s2 = ps [(size_t)c * B_N + j];
        float nm = fmaxf(m, m2);
        s = s * exp2fast(m - nm) + s2 * exp2fast(m2 - nm);
        m = nm;
    }
    int lab = labels[j];
    atomicAdd(&csL[lab], s);
    atomicAdd(&ccL[lab], 1u);
    __syncthreads();
    if (t < NCLS) {
        partSum[blockIdx.x * NCLS + t] = csL[t];
        partCnt[blockIdx.x * NCLS + t] = ccL[t];
    }
}

__global__ void loss_kernel(const float* __restrict__ partSum,
                            const unsigned int* __restrict__ partCnt,
                            float* __restrict__ out)
{
    int c = threadIdx.x;  // 64 threads = 1 wave
    float cs = 0.0f;
    unsigned int cc = 0u;
    if (c < NCLS) {
#pragma unroll 4
        for (int b = 0; b < NPBLK; ++b) {
            cs += partSum[b * NCLS + c];
            cc += partCnt[b * NCLS + c];
        }
    }

    float tot = cs;
#pragma unroll
    for (int off = 1; off < 64; off <<= 1) tot += __shfl_xor(tot, off);

    float contrib = 0.0f;
    if (c < NCLS && cc > 0u) {
        float negc = (float)(B_N - (int)cc);
        float nds  = tot - cs;
        float x    = (negc > 0.0f) ? (nds / negc) : nds;
        float lp   = (cc >= 2u) ? (-logf(x + 1e-12f)) : 0.0f;
        contrib = (float)cc * lp;
    }
#pragma unroll
    for (int off = 1; off < 64; off <<= 1) contrib += __shfl_xor(contrib, off);
    if (c == 0) out[0] = -(contrib / (float)B_N);
}

extern "C" void kernel_launch(void* const* d_in, const int* in_sizes, int n_in,
                              void* d_out, int out_size, void* d_ws, size_t ws_size,
                              hipStream_t stream)
{
    const float* anchor = (const float*)d_in[0];
    const float* target = (const float*)d_in[1];
    const int*   labels = (const int*)d_in[2];
    float* out = (float*)d_out;

    const size_t PLANE = (size_t)B_N * K_AUG * sizeof(short);   // 3 MB
    char* ws = (char*)d_ws;
    short* aH = (short*)(ws + 0 * PLANE);
    short* bT = (short*)(ws + 1 * PLANE);
    float* ps  = (float*)(ws + 2 * PLANE);
    float* pmx = (float*)(ws + 2 * PLANE + sizeof(float) * NCHUNK * B_N);
    char*  cls = ws + 2 * PLANE + 2 * sizeof(float) * NCHUNK * B_N;
    float*        partSum = (float*)cls;
    unsigned int* partCnt = (unsigned int*)(cls + NPBLK * NCLS * sizeof(float));

    const int nprep = B_N * NKQ + B_N;              // 204800
    prep_kernel<<<nprep / 256, 256, 0, stream>>>(anchor, target, labels, aH, bT);
    rowstats_kernel<<<(B_N / 128) * NCHUNK, 256, 0, stream>>>(aH, bT, pmx, ps);
    classsum_kernel<<<B_N / 256, 256, 0, stream>>>(pmx, ps, labels, partSum, partCnt);
    loss_kernel<<<1, 64, 0, stream>>>(partSum, partCnt, out);
}